// Round 5
// baseline (1377.771 us; speedup 1.0000x reference)
//
#include <hip/hip_runtime.h>
#include <math.h>

// Soft-DTW (gamma=0.1), 4096x4096, wave-parallel band pipeline v3.
// 8 workgroups x 8 waves (512 thr). Wave w of WG g = band 8g+w = rows
// [512g+64w, 512g+64w+63]; lane l = row band*64+l; lane l at step t computes
// cell (row, t-l). up/diag via DPP wave_shr:1. Scaled log2 domain R'=R/(g*ln2).
// v3: intra-WG handoffs (56 of 63) via LDS value-as-flag (poll RT ~60cy,
// kills the spin-ratchet + HBM round-trips seen in v2); only 7 handoffs stay
// global (relaxed agent atomics, 2-chunk-ahead sample margin > HBM RT).

#define KS     14.426950408889634f   // 1/(0.1*ln2)
#define BIGP   1.4426950e+11f        // 1e10 * KS
#define NN     4096
#define POISON 0xAAAAAAAAu           // ws/LDS poison; boundary values never this
#define YPADF  64
#define YPADB  192
#define YTOT   (YPADF + NN + YPADB)  // 4352 floats

__device__ __forceinline__ float dpp_shr1(float oldv, float src) {
    // lanes 1..63 <- src[lane-1]; lane 0 keeps oldv (bound_ctrl=false)
    int o = __float_as_int(oldv), s = __float_as_int(src);
    return __int_as_float(__builtin_amdgcn_update_dpp(o, s, 0x138 /*wave_shr:1*/, 0xF, 0xF, false));
}
__device__ __forceinline__ float rdlane(float v, int l) {
    return __int_as_float(__builtin_amdgcn_readlane(__float_as_int(v), l));
}
__device__ __forceinline__ float aloadG(const float* p) {
    unsigned u = __hip_atomic_load((const unsigned*)p, __ATOMIC_RELAXED, __HIP_MEMORY_SCOPE_AGENT);
    return __uint_as_float(u);
}
__device__ __forceinline__ void astoreG(float* p, float v) {
    __hip_atomic_store((unsigned*)p, __float_as_uint(v), __ATOMIC_RELAXED, __HIP_MEMORY_SCOPE_AGENT);
}
__device__ __forceinline__ float aloadL(const float* p) {
    unsigned u = __hip_atomic_load((const unsigned*)p, __ATOMIC_RELAXED, __HIP_MEMORY_SCOPE_WORKGROUP);
    return __uint_as_float(u);
}
__device__ __forceinline__ void astoreL(float* p, float v) {
    __hip_atomic_store((unsigned*)p, __float_as_uint(v), __ATOMIC_RELAXED, __HIP_MEMORY_SCOPE_WORKGROUP);
}

__global__ __launch_bounds__(512, 1)
void sdtw_band_kernel(const float* __restrict__ x, const float* __restrict__ y,
                      float* __restrict__ out, float* __restrict__ bndG,
                      float* __restrict__ yws) {
    __shared__ float shb[7][NN];                 // 112 KiB intra-WG boundary rows
    const int g    = blockIdx.x;
    const int tid  = threadIdx.x;
    const int w    = tid >> 6;
    const int lane = tid & 63;
    const int band = g * 8 + w;
    const float sqK = sqrtf(KS);

    // ---- init: poison LDS handoff rows; stage padded y*sqrt(K) into ws ----
    {
        unsigned* shu = (unsigned*)&shb[0][0];
        for (int i = tid; i < 7 * NN; i += 512) shu[i] = POISON;
        float* yp0 = yws + g * YTOT;             // per-WG private copy (same XCD L2)
        for (int i = tid; i < YTOT; i += 512) {
            int yi = i - YPADF;
            yp0[i] = (yi >= 0 && yi < NN) ? y[yi] * sqK : 0.0f;
        }
    }
    __syncthreads();

    const float* yp = yws + g * YTOT;
    const float xs = x[band * 64 + lane] * sqK;

    const bool consL = (w > 0);
    const bool consG = (w == 0 && g > 0);
    const bool prodL = (w < 7);
    const bool prodG = (w == 7 && g < 7);
    float*       gout = bndG + g * NN;
    const float* gin  = bndG + (g > 0 ? (g - 1) : 0) * NN;
    const float* lin  = &shb[(w > 0 ? w - 1 : 0)][0];
    float*       lout = &shb[(w < 7 ? w : 0)][0];

    float r1  = BIGP;                                   // own R' at t-1
    float vdg = (band == 0 && lane == 0) ? 0.0f : BIGP; // prev shifted-up (diag)
    float rsave = 0.0f;
    float yw[16], ywn[16];
    float bcur = 0.0f, bnx = 0.0f;

    // ---- prime chunk 0 ----------------------------------------------------
    #pragma unroll
    for (int k = 0; k < 16; ++k) yw[k] = yp[YPADF + k - lane];
    if (consG) { bcur = aloadG(&gin[lane & 15]); bnx = aloadG(&gin[16 + (lane & 15)]); }
    if (consL) { bcur = aloadL(&lin[lane & 15]); }

    for (int c = 0; c < 260; ++c) {                     // 260*16 = 4160 steps
        const int base = c * 16;
        const int li   = base + (lane & 15);
        // ---- readiness check for current chunk (value-as-flag) ------------
        if (consL && c <= 255) {
            int bail = 0;
            while ((__ballot(__float_as_uint(bcur) != POISON) & 0xFFFFull) != 0xFFFFull) {
                __builtin_amdgcn_s_sleep(1);
                bcur = aloadL(&lin[li]);
                if (++bail > (1 << 20)) break;
            }
            if (c < 255) bnx = aloadL(&lin[li + 16]);   // 1-ahead (RT ~60cy)
        } else if (consG && c <= 255) {
            int bail = 0;
            while ((__ballot(__float_as_uint(bcur) != POISON) & 0xFFFFull) != 0xFFFFull) {
                __builtin_amdgcn_s_sleep(1);
                bcur = aloadG(&gin[li]);
                if (++bail > (1 << 20)) break;
            }
        }
        float btmp = 0.0f;
        if (consG && c < 254) btmp = aloadG(&gin[li + 32]);  // 2-ahead sample
        {   // y window for next chunk (ws, XCD-L2 resident)
            const float* yb = yp + YPADF + base + 16 - lane;
            #pragma unroll
            for (int k = 0; k < 16; ++k) ywn[k] = yb[k];
        }
        // ---- 16 DP steps --------------------------------------------------
        #pragma unroll
        for (int s = 0; s < 16; ++s) {
            float binj = (consL || consG) ? rdlane(bcur, s) : BIGP;
            float vup  = dpp_shr1(binj, r1);            // R'[i-1][j]
            float m    = fminf(fminf(vup, vdg), r1);    // min3
            float e1 = __builtin_amdgcn_exp2f(m - vup);
            float e3 = __builtin_amdgcn_exp2f(m - vdg);
            float e2 = __builtin_amdgcn_exp2f(m - r1);
            float lg = __builtin_amdgcn_logf((e1 + e3) + e2);   // log2
            float diff = xs - yw[s];
            float rn = fmaf(diff, diff, m) - lg;        // d' + softmin'
            vdg = vup;
            r1  = rn;
            const int t = base + s;
            if (lane == 63 && t >= 63 && t <= 63 + NN - 1) {
                if (prodL) astoreL(&lout[t - 63], rn);  // LDS handoff
                if (prodG) astoreG(&gout[t - 63], rn);  // cross-WG via LLC/HBM
            }
            if (s == 14 && c == 259) rsave = rn;        // t=4158: R'[4095][4095]
        }
        // ---- rotate -------------------------------------------------------
        if (consG) { bcur = bnx; bnx = btmp; }
        else if (consL) { bcur = bnx; }
        #pragma unroll
        for (int k = 0; k < 16; ++k) yw[k] = ywn[k];
    }

    if (band == 63 && lane == 63)
        out[0] = fabsf(rsave * (1.0f / KS));
}

extern "C" void kernel_launch(void* const* d_in, const int* in_sizes, int n_in,
                              void* d_out, int out_size, void* d_ws, size_t ws_size,
                              hipStream_t stream) {
    const float* x = (const float*)d_in[0];   // "inputs"  (rows)
    const float* y = (const float*)d_in[1];   // "targets" (cols)
    float* out = (float*)d_out;
    float* bndG = (float*)d_ws;                       // 8*4096*4 = 128 KiB
    float* yws  = (float*)d_ws + 8 * NN;              // 8*4352*4 = 136 KiB
    sdtw_band_kernel<<<dim3(8), dim3(512), 0, stream>>>(x, y, out, bndG, yws);
}